// Round 11
// baseline (253.196 us; speedup 1.0000x reference)
//
#include <hip/hip_runtime.h>

typedef int v4i __attribute__((ext_vector_type(4)));

constexpr int Kdim = 4096;
constexpr int Ndim = 4096;
constexpr int MtotC = 8192;
constexpr int BM = 256;
constexpr int BN = 256;
constexpr int BKB = 128;          // K-bytes per LDS tile (2 halves of 64B)
constexpr int NT = Kdim / BKB;    // 32 K-tiles

// ---------------- pack int32 -> int8 (both tensors, one launch) ----------------
__global__ void pack_i32_to_i8(const int* __restrict__ xq, const int* __restrict__ wq,
                               signed char* __restrict__ x8, signed char* __restrict__ w8,
                               size_t nx4, size_t nw4) {
    size_t i = (size_t)blockIdx.x * blockDim.x + threadIdx.x;
    size_t stride = (size_t)gridDim.x * blockDim.x;
    size_t tot = nx4 + nw4;
    for (size_t j = i; j < tot; j += stride) {
        if (j < nx4) {
            const int4 v = ((const int4*)xq)[j];
            char4 c;
            c.x = (signed char)v.x; c.y = (signed char)v.y;
            c.z = (signed char)v.z; c.w = (signed char)v.w;
            ((char4*)x8)[j] = c;
        } else {
            const size_t k = j - nx4;
            const int4 v = ((const int4*)wq)[k];
            char4 c;
            c.x = (signed char)v.x; c.y = (signed char)v.y;
            c.z = (signed char)v.z; c.w = (signed char)v.w;
            ((char4*)w8)[k] = c;
        }
    }
}

// ---------------- int8 GEMM, 256x256 tile, 4 waves of 128x128 ----------------
// ops/LDS-byte = 128 (vs 85 at 128x64 wave tiles): LDS reads 128KB + writes 64KB
// per 128B-K-tile per CU ~ 1714 cyc < MFMA floor 2613 cyc -> MFMA-bound geometry.
// 1 wave/SIMD (acc 256 VGPR); flat 32 ds_read + 128 MFMA per tile, compiler
// fine-grained lgkmcnt overlaps reads with MFMAs. Counted vmcnt(16) staging.
// LDS: 2 bufs x 2 halves x (A 16KB + B 16KB) = 128KB.
// 16B-slot swizzle within a 64B row: slot' = slot ^ ((row>>1)&3)  (verified 0-conflict).
__global__ __launch_bounds__(256, 1) void i8gemm_kernel(
    const signed char* __restrict__ A,
    const signed char* __restrict__ W,
    const float* __restrict__ sx,
    const float* __restrict__ wsc,
    const float* __restrict__ bias,
    float* __restrict__ C)
{
    extern __shared__ signed char smem[];

    const int tid  = threadIdx.x;
    const int wave = tid >> 6;
    const int lane = tid & 63;
    const int wr = wave >> 1;     // 0..1  (128-row strip)
    const int wc = wave & 1;      // 0..1  (128-col strip)

    // XCD-aware swizzle: 8 regions of 8bm x 8bn
    const int xr_ = blockIdx.x & 7;
    const int idx = blockIdx.x >> 3;
    const int bm = ((xr_ & 3) * 8 + (idx & 7)) * BM;
    const int bn = ((xr_ >> 2) * 8 + (idx >> 3)) * BN;

    // ---- staging constants ----
    // thread t covers rows (t>>2)+64r, r=0..3, slot' = t&3; LDS dest = r*4096 + t*16 (linear).
    const int srow = tid >> 2;                              // 0..63
    const int gslot = (tid & 3) ^ ((tid >> 3) & 3);         // pre-inverse-swizzled 16B slot
    const signed char* Ag = A + (size_t)(bm + srow) * Kdim + gslot * 16;
    const signed char* Wg = W + (size_t)(bn + srow) * Kdim + gslot * 16;

    // ---- fragment read constants (16x16x64: row/col = lane&15, 16B k-slot = lane>>4) ----
    const int frow = lane & 15;
    const int fsl  = lane >> 4;
    const int rsw  = ((fsl ^ ((frow >> 1) & 3)) << 4);      // swizzled 16B slot byte
    const int aro  = (wr * 128 + frow) * 64 + rsw;          // + f*1024 + half*32768
    const int bro  = 16384 + (wc * 128 + frow) * 64 + rsw;  // + g*1024 + half*32768

    v4i acc[8][8];
#pragma unroll
    for (int f = 0; f < 8; ++f)
#pragma unroll
        for (int g = 0; g < 8; ++g)
#pragma unroll
            for (int e = 0; e < 4; ++e) acc[f][g][e] = 0;

    // 16 global_load_lds per thread per K-tile (2 halves x (4 A-rowblocks + 4 B-rowblocks))
#define STG(KT) do {                                                                   \
    signed char* dst = smem + ((KT) & 1) * 65536;                                      \
    const size_t ko = (size_t)(KT) * BKB;                                              \
    _Pragma("unroll") for (int h = 0; h < 2; ++h) {                                    \
        _Pragma("unroll") for (int r = 0; r < 4; ++r)                                  \
            __builtin_amdgcn_global_load_lds(                                          \
                (const __attribute__((address_space(1))) void*)(Ag + (size_t)(r * 64) * Kdim + ko + h * 64), \
                (__attribute__((address_space(3))) void*)(dst + h * 32768 + r * 4096 + tid * 16), 16, 0, 0); \
        _Pragma("unroll") for (int r = 0; r < 4; ++r)                                  \
            __builtin_amdgcn_global_load_lds(                                          \
                (const __attribute__((address_space(1))) void*)(Wg + (size_t)(r * 64) * Kdim + ko + h * 64), \
                (__attribute__((address_space(3))) void*)(dst + h * 32768 + 16384 + r * 4096 + tid * 16), 16, 0, 0); \
    }                                                                                  \
} while (0)

#define BAR __builtin_amdgcn_s_barrier()

    // ---- prologue: stage tiles 0,1 (32 loads/thread); drain tile 0 ----
    STG(0);
    STG(1);
    asm volatile("s_waitcnt vmcnt(16)" ::: "memory");
    BAR;

    for (int u = 0; u < NT; ++u) {
        const signed char* bufb = smem + (u & 1) * 65536;

        // ---- 32 ds_read_b128 + 128 MFMA, compiler-scheduled ----
        v4i av0[8], bv0[8], av1[8], bv1[8];
#pragma unroll
        for (int g = 0; g < 8; ++g) bv0[g] = *(const v4i*)(bufb + bro + g * 1024);
#pragma unroll
        for (int f = 0; f < 8; ++f) av0[f] = *(const v4i*)(bufb + aro + f * 1024);
#pragma unroll
        for (int g = 0; g < 8; ++g) bv1[g] = *(const v4i*)(bufb + 32768 + bro + g * 1024);
#pragma unroll
        for (int f = 0; f < 8; ++f) av1[f] = *(const v4i*)(bufb + 32768 + aro + f * 1024);

#pragma unroll
        for (int f = 0; f < 8; ++f)
#pragma unroll
            for (int g = 0; g < 8; ++g)
                acc[f][g] = __builtin_amdgcn_mfma_i32_16x16x64_i8(av0[f], bv0[g], acc[f][g], 0, 0, 0);
#pragma unroll
        for (int f = 0; f < 8; ++f)
#pragma unroll
            for (int g = 0; g < 8; ++g)
                acc[f][g] = __builtin_amdgcn_mfma_i32_16x16x64_i8(av1[f], bv1[g], acc[f][g], 0, 0, 0);

        BAR;   // all 4 waves done reading buf[u&1]

        if (u + 2 < NT) {
            STG(u + 2);                                          // -> buf[u&1]
            asm volatile("s_waitcnt vmcnt(16)" ::: "memory");    // tile u+1 landed
            BAR;
        } else if (u + 1 < NT) {
            asm volatile("s_waitcnt vmcnt(0)" ::: "memory");     // last tile landed
            BAR;
        }
    }

    // ---- epilogue: dequant + bias, fp32 store ----
    // 16x16 C/D map: col = lane&15, row = (lane>>4)*4 + reg
    const int orow0 = bm + wr * 128;
    const int ocol0 = bn + wc * 128;
    float wsv[8], bvv[8];
#pragma unroll
    for (int g = 0; g < 8; ++g) {
        const int col = ocol0 + g * 16 + frow;
        wsv[g] = wsc[col];
        bvv[g] = bias[col];
    }
#pragma unroll
    for (int f = 0; f < 8; ++f) {
#pragma unroll
        for (int jr = 0; jr < 4; ++jr) {
            const int row = orow0 + f * 16 + fsl * 4 + jr;
            const float s = sx[row];
#pragma unroll
            for (int g = 0; g < 8; ++g) {
                const int col = ocol0 + g * 16 + frow;
                C[(size_t)row * Ndim + col] = (float)acc[f][g][jr] * s * wsv[g] + bvv[g];
            }
        }
    }
#undef STG
#undef BAR
}

extern "C" void kernel_launch(void* const* d_in, const int* in_sizes, int n_in,
                              void* d_out, int out_size, void* d_ws, size_t ws_size,
                              hipStream_t stream) {
    (void)in_sizes; (void)n_in; (void)out_size; (void)ws_size;
    const int*   x_q  = (const int*)d_in[0];
    const float* sx   = (const float*)d_in[1];
    const int*   w_q  = (const int*)d_in[2];
    const float* wsc  = (const float*)d_in[3];
    const float* bias = (const float*)d_in[4];
    float* out = (float*)d_out;

    signed char* x8 = (signed char*)d_ws;
    signed char* w8 = x8 + (size_t)MtotC * Kdim;

    const size_t nx = (size_t)MtotC * Kdim;   // 32 Mi
    const size_t nw = (size_t)Ndim * Kdim;    // 16 Mi

    pack_i32_to_i8<<<3072, 256, 0, stream>>>(x_q, w_q, x8, w8, nx / 4, nw / 4);

    static bool attr_set = false;
    if (!attr_set) {
        hipFuncSetAttribute((const void*)i8gemm_kernel,
                            hipFuncAttributeMaxDynamicSharedMemorySize, 131072);
        attr_set = true;
    }

    const int nwg = (MtotC / BM) * (Ndim / BN);  // 512
    i8gemm_kernel<<<nwg, 256, 131072, stream>>>(x8, w8, sx, wsc, bias, out);
}

// Round 12
// 217.326 us; speedup vs baseline: 1.1651x; 1.1651x over previous
//
#include <hip/hip_runtime.h>

typedef int v4i __attribute__((ext_vector_type(4)));

constexpr int Kdim = 4096;
constexpr int Ndim = 4096;
constexpr int MtotC = 8192;
constexpr int BM = 256;
constexpr int BN = 256;
constexpr int BKB = 128;          // K-bytes per K-tile (2 halves of 64B)
constexpr int NT = Kdim / BKB;    // 32 K-tiles

// ---------------- pack int32 -> int8 (both tensors, one launch) ----------------
__global__ void pack_i32_to_i8(const int* __restrict__ xq, const int* __restrict__ wq,
                               signed char* __restrict__ x8, signed char* __restrict__ w8,
                               size_t nx4, size_t nw4) {
    size_t i = (size_t)blockIdx.x * blockDim.x + threadIdx.x;
    size_t stride = (size_t)gridDim.x * blockDim.x;
    size_t tot = nx4 + nw4;
    for (size_t j = i; j < tot; j += stride) {
        if (j < nx4) {
            const int4 v = ((const int4*)xq)[j];
            char4 c;
            c.x = (signed char)v.x; c.y = (signed char)v.y;
            c.z = (signed char)v.z; c.w = (signed char)v.w;
            ((char4*)x8)[j] = c;
        } else {
            const size_t k = j - nx4;
            const int4 v = ((const int4*)wq)[k];
            char4 c;
            c.x = (signed char)v.x; c.y = (signed char)v.y;
            c.z = (signed char)v.z; c.w = (signed char)v.w;
            ((char4*)w8)[k] = c;
        }
    }
}

// ---------------- int8 GEMM, 256x256 tile, A via LDS, B direct global->reg ----------------
// Per wave (8 waves, 128x64 tiles): B strip is wave-private -> no LDS for B (cuts
// LDS traffic 256KB -> 160KB per K-tile per CU, below the 2613-cyc MFMA floor).
// A: 2 bufs x 2 halves x 16KB = 64KB LDS, 16B-slot swizzle slot' = slot ^ ((row>>1)&3)
// (hardware-verified 0-conflict). B: per-lane global dwordx4, compiler-managed vmcnt.
// Manual vmcnt counts only A staging (4 loads/thread/tile).
__global__ __launch_bounds__(512, 2) void i8gemm_kernel(
    const signed char* __restrict__ A,
    const signed char* __restrict__ W,
    const float* __restrict__ sx,
    const float* __restrict__ wsc,
    const float* __restrict__ bias,
    float* __restrict__ C)
{
    __shared__ signed char smem[65536];

    const int tid  = threadIdx.x;
    const int wave = tid >> 6;
    const int lane = tid & 63;
    const int wr = wave >> 2;     // 0..1  (128-row strip)
    const int wc = wave & 3;      // 0..3  (64-col strip, wave-private B)

    // XCD-aware swizzle: 8 regions of 8bm x 8bn
    const int xr_ = blockIdx.x & 7;
    const int idx = blockIdx.x >> 3;
    const int bm = ((xr_ & 3) * 8 + (idx & 7)) * BM;
    const int bn = ((xr_ >> 2) * 8 + (idx >> 3)) * BN;

    // ---- A staging constants (4 gload_lds per thread per K-tile) ----
    const int srow  = tid >> 2;                             // 0..127
    const int gslot = (tid & 3) ^ ((srow >> 1) & 3);        // pre-inverse-swizzled 16B slot
    const signed char* Ag = A + (size_t)(bm + srow) * Kdim + gslot * 16;
    // dst(h, r) = buf*32768 + h*16384 + r*8192 + tid*16   (linear, gload_lds-safe)

    // ---- fragment read constants (16x16x64: row/col = lane&15, 16B k-slot = lane>>4) ----
    const int frow = lane & 15;
    const int fsl  = lane >> 4;
    const int rsw  = ((fsl ^ ((frow >> 1) & 3)) << 4);      // swizzled 16B slot byte
    const int aro  = (wr * 128 + frow) * 64 + rsw;          // + f*1024 + h*16384

    // ---- B direct-load base (wave-private cols) ----
    const signed char* Bg = W + (size_t)(bn + wc * 64 + frow) * Kdim + fsl * 16;
    // load(g, u, h) = *(v4i*)(Bg + g*65536 + u*128 + h*64)

    v4i acc[8][4];
#pragma unroll
    for (int f = 0; f < 8; ++f)
#pragma unroll
        for (int g = 0; g < 4; ++g)
#pragma unroll
            for (int e = 0; e < 4; ++e) acc[f][g][e] = 0;

    v4i bh0[4], bh1[4];

#define STG_A(KT) do {                                                                 \
    signed char* dst = smem + ((KT) & 1) * 32768 + tid * 16;                           \
    const size_t ko = (size_t)(KT) * BKB;                                              \
    _Pragma("unroll") for (int h = 0; h < 2; ++h)                                      \
    _Pragma("unroll") for (int r = 0; r < 2; ++r)                                      \
        __builtin_amdgcn_global_load_lds(                                              \
            (const __attribute__((address_space(1))) void*)(Ag + (size_t)(r * 128) * Kdim + ko + h * 64), \
            (__attribute__((address_space(3))) void*)(dst + h * 16384 + r * 8192), 16, 0, 0); \
} while (0)

#define BAR __builtin_amdgcn_s_barrier()

    // ---- prologue: Bh0(0); stage A(0), A(1); drain Bh0(0)+A(0) ----
#pragma unroll
    for (int g = 0; g < 4; ++g) bh0[g] = *(const v4i*)(Bg + g * 65536);
    STG_A(0);
    STG_A(1);
    asm volatile("s_waitcnt vmcnt(4)" ::: "memory");   // leaves A(1)
    BAR;

#define TILE(U, DOB0, DOS, DOTAIL) do {                                                \
    const signed char* bufb = smem + ((U) & 1) * 32768;                                \
    /* issue B(U).h1 (compiler-managed wait before h1 MFMAs) */                        \
    _Pragma("unroll") for (int g = 0; g < 4; ++g)                                      \
        bh1[g] = *(const v4i*)(Bg + g * 65536 + (U) * 128 + 64);                       \
    /* half 0: 8 A ds_reads + 32 MFMA */                                               \
    {                                                                                  \
        v4i av[8];                                                                     \
        _Pragma("unroll") for (int f = 0; f < 8; ++f)                                  \
            av[f] = *(const v4i*)(bufb + aro + f * 1024);                              \
        __builtin_amdgcn_s_setprio(1);                                                 \
        _Pragma("unroll") for (int f = 0; f < 8; ++f)                                  \
        _Pragma("unroll") for (int g = 0; g < 4; ++g)                                  \
            acc[f][g] = __builtin_amdgcn_mfma_i32_16x16x64_i8(av[f], bh0[g], acc[f][g], 0, 0, 0); \
        __builtin_amdgcn_s_setprio(0);                                                 \
    }                                                                                  \
    __builtin_amdgcn_sched_barrier(0);                                                 \
    /* issue B(U+1).h0 (lands before next tile's h0 MFMAs) */                          \
    if (DOB0) {                                                                        \
        _Pragma("unroll") for (int g = 0; g < 4; ++g)                                  \
            bh0[g] = *(const v4i*)(Bg + g * 65536 + ((U) + 1) * 128);                  \
    }                                                                                  \
    /* half 1: 8 A ds_reads + 32 MFMA */                                               \
    {                                                                                  \
        v4i av[8];                                                                     \
        _Pragma("unroll") for (int f = 0; f < 8; ++f)                                  \
            av[f] = *(const v4i*)(bufb + 16384 + aro + f * 1024);                      \
        __builtin_amdgcn_s_setprio(1);                                                 \
        _Pragma("unroll") for (int f = 0; f < 8; ++f)                                  \
        _Pragma("unroll") for (int g = 0; g < 4; ++g)                                  \
            acc[f][g] = __builtin_amdgcn_mfma_i32_16x16x64_i8(av[f], bh1[g], acc[f][g], 0, 0, 0); \
        __builtin_amdgcn_s_setprio(0);                                                 \
    }                                                                                  \
    if (DOTAIL) {                                                                      \
        BAR;                                                                           \
        if (DOS) {                                                                     \
            STG_A((U) + 2);                                                            \
            asm volatile("s_waitcnt vmcnt(4)" ::: "memory");  /* leaves A(U+2) */      \
        } else {                                                                       \
            asm volatile("s_waitcnt vmcnt(0)" ::: "memory");                           \
        }                                                                              \
        BAR;                                                                           \
    }                                                                                  \
} while (0)

    for (int u = 0; u < NT - 2; ++u)
        TILE(u, true, true, true);
    TILE(NT - 2, true, false, true);    // loads B(31).h0-chain done; drain-all tail
    TILE(NT - 1, false, false, false);  // compute only

    // ---- epilogue: dequant + bias, fp32 store ----
    // 16x16 C/D map: col = lane&15, row = (lane>>4)*4 + reg
    const int orow0 = bm + wr * 128;
    const int ocol0 = bn + wc * 64;
    float wsv[4], bvv[4];
#pragma unroll
    for (int g = 0; g < 4; ++g) {
        const int col = ocol0 + g * 16 + frow;
        wsv[g] = wsc[col];
        bvv[g] = bias[col];
    }
#pragma unroll
    for (int f = 0; f < 8; ++f) {
#pragma unroll
        for (int jr = 0; jr < 4; ++jr) {
            const int row = orow0 + f * 16 + fsl * 4 + jr;
            const float s = sx[row];
#pragma unroll
            for (int g = 0; g < 4; ++g) {
                const int col = ocol0 + g * 16 + frow;
                C[(size_t)row * Ndim + col] = (float)acc[f][g][jr] * s * wsv[g] + bvv[g];
            }
        }
    }
#undef STG_A
#undef BAR
#undef TILE
}

extern "C" void kernel_launch(void* const* d_in, const int* in_sizes, int n_in,
                              void* d_out, int out_size, void* d_ws, size_t ws_size,
                              hipStream_t stream) {
    (void)in_sizes; (void)n_in; (void)out_size; (void)ws_size;
    const int*   x_q  = (const int*)d_in[0];
    const float* sx   = (const float*)d_in[1];
    const int*   w_q  = (const int*)d_in[2];
    const float* wsc  = (const float*)d_in[3];
    const float* bias = (const float*)d_in[4];
    float* out = (float*)d_out;

    signed char* x8 = (signed char*)d_ws;
    signed char* w8 = x8 + (size_t)MtotC * Kdim;

    const size_t nx = (size_t)MtotC * Kdim;   // 32 Mi
    const size_t nw = (size_t)Ndim * Kdim;    // 16 Mi

    pack_i32_to_i8<<<3072, 256, 0, stream>>>(x_q, w_q, x8, w8, nx / 4, nw / 4);

    const int nwg = (MtotC / BM) * (Ndim / BN);  // 512
    i8gemm_kernel<<<nwg, 512, 0, stream>>>(x8, w8, sx, wsc, bias, out);
}

// Round 13
// 187.851 us; speedup vs baseline: 1.3479x; 1.1569x over previous
//
#include <hip/hip_runtime.h>

typedef int v4i __attribute__((ext_vector_type(4)));

constexpr int Kdim = 4096;
constexpr int Ndim = 4096;
constexpr int MtotC = 8192;
constexpr int BM = 256;
constexpr int BN = 256;
constexpr int BKB = 128;          // K-bytes per K-tile (2 halves of 64B)
constexpr int NT = Kdim / BKB;    // 32 K-tiles

#define AS1 __attribute__((address_space(1)))
#define AS3 __attribute__((address_space(3)))

// ---------------- pack int32 -> int8 (both tensors, one launch) ----------------
__global__ void pack_i32_to_i8(const int* __restrict__ xq, const int* __restrict__ wq,
                               signed char* __restrict__ x8, signed char* __restrict__ w8,
                               size_t nx4, size_t nw4) {
    size_t i = (size_t)blockIdx.x * blockDim.x + threadIdx.x;
    size_t stride = (size_t)gridDim.x * blockDim.x;
    size_t tot = nx4 + nw4;
    for (size_t j = i; j < tot; j += stride) {
        if (j < nx4) {
            const int4 v = ((const int4*)xq)[j];
            char4 c;
            c.x = (signed char)v.x; c.y = (signed char)v.y;
            c.z = (signed char)v.z; c.w = (signed char)v.w;
            ((char4*)x8)[j] = c;
        } else {
            const size_t k = j - nx4;
            const int4 v = ((const int4*)wq)[k];
            char4 c;
            c.x = (signed char)v.x; c.y = (signed char)v.y;
            c.z = (signed char)v.z; c.w = (signed char)v.w;
            ((char4*)w8)[k] = c;
        }
    }
}

// ---------------- int8 GEMM, 256x256, register-double-buffered phases ----------------
// Phase p: vmcnt(8); barrier; stage half p+4; 12 ds_reads (half p+1) -> spare regset;
// 32 MFMA on current regset (operands read in phase p-1 -> NO lgkm gate on MFMA);
// lgkmcnt(0). LDS port drains reads DURING the MFMA window -> pipes overlap.
// LDS: 2 bufs x 2 halves x (A 16KB + B 16KB) = 128KB.
// 16B-slot swizzle within a 64B row: slot' = slot ^ ((row>>1)&3)  (verified 0-conflict).
__global__ __launch_bounds__(512, 2) void i8gemm_kernel(
    const signed char* __restrict__ A,
    const signed char* __restrict__ W,
    const float* __restrict__ sx,
    const float* __restrict__ wsc,
    const float* __restrict__ bias,
    float* __restrict__ C)
{
    extern __shared__ signed char smem[];

    const int tid  = threadIdx.x;
    const int wave = tid >> 6;
    const int lane = tid & 63;
    const int wr = wave >> 2;     // 0..1  (128-row strip)
    const int wc = wave & 3;      // 0..3  (64-col strip)

    // XCD-aware swizzle: 8 regions of 8bm x 8bn
    const int xr_ = blockIdx.x & 7;
    const int idx = blockIdx.x >> 3;
    const int bm = ((xr_ & 3) * 8 + (idx & 7)) * BM;
    const int bn = ((xr_ >> 2) * 8 + (idx >> 3)) * BN;

    // ---- staging constants (4 gload_lds per thread per half-stage) ----
    const int srow  = tid >> 2;                             // 0..127
    const int gslot = (tid & 3) ^ ((srow >> 1) & 3);        // pre-inverse-swizzled 16B slot
    const signed char* Ag = A + (size_t)(bm + srow) * Kdim + gslot * 16;
    const signed char* Wg = W + (size_t)(bn + srow) * Kdim + gslot * 16;
    const int sdst = srow * 64 + (tid & 3) * 16;            // linear lane-contiguous dest

    // ---- fragment read constants (16x16x64: row/col = lane&15, 16B k-slot = lane>>4) ----
    const int frow = lane & 15;
    const int fsl  = lane >> 4;
    const int rsw  = ((fsl ^ ((frow >> 1) & 3)) << 4);      // swizzled 16B slot byte
    const int aro  = (wr * 128 + frow) * 64 + rsw;          // + f*1024 + half*32768
    const int bro  = 16384 + (wc * 64 + frow) * 64 + rsw;   // + g*1024 + half*32768

    v4i acc[8][4];
#pragma unroll
    for (int f = 0; f < 8; ++f)
#pragma unroll
        for (int g = 0; g < 4; ++g)
#pragma unroll
            for (int e = 0; e < 4; ++e) acc[f][g][e] = 0;

    v4i avA[8], bvA[4], avB[8], bvB[4];   // static ping-pong (rule #20)

#define STG_HALF(KT, HALF) do {                                                        \
    signed char* dst = smem + ((KT) & 1) * 65536 + (HALF) * 32768 + sdst;              \
    const signed char* sa = Ag + (size_t)(KT) * BKB + (HALF) * 64;                     \
    const signed char* sb = Wg + (size_t)(KT) * BKB + (HALF) * 64;                     \
    __builtin_amdgcn_global_load_lds((const AS1 void*)sa,                  (AS3 void*)dst,           16, 0, 0); \
    __builtin_amdgcn_global_load_lds((const AS1 void*)(sa + (size_t)128 * Kdim), (AS3 void*)(dst + 8192),  16, 0, 0); \
    __builtin_amdgcn_global_load_lds((const AS1 void*)sb,                  (AS3 void*)(dst + 16384), 16, 0, 0); \
    __builtin_amdgcn_global_load_lds((const AS1 void*)(sb + (size_t)128 * Kdim), (AS3 void*)(dst + 24576), 16, 0, 0); \
} while (0)

#define READ_SET(AV, BV, BASE, HALF) do {                                              \
    _Pragma("unroll") for (int g_ = 0; g_ < 4; ++g_)                                   \
        BV[g_] = *(const v4i*)((BASE) + (HALF) * 32768 + bro + g_ * 1024);             \
    _Pragma("unroll") for (int f_ = 0; f_ < 8; ++f_)                                   \
        AV[f_] = *(const v4i*)((BASE) + (HALF) * 32768 + aro + f_ * 1024);             \
} while (0)

#define MFMA_SET(AV, BV) do {                                                          \
    __builtin_amdgcn_s_setprio(1);                                                     \
    _Pragma("unroll") for (int f_ = 0; f_ < 8; ++f_)                                   \
    _Pragma("unroll") for (int g_ = 0; g_ < 4; ++g_)                                   \
        acc[f_][g_] = __builtin_amdgcn_mfma_i32_16x16x64_i8(AV[f_], BV[g_], acc[f_][g_], 0, 0, 0); \
    __builtin_amdgcn_s_setprio(0);                                                     \
} while (0)

#define BAR   __builtin_amdgcn_s_barrier()
#define LGKM0 asm volatile("s_waitcnt lgkmcnt(0)" ::: "memory")

    // ---- prologue: stage halves 0H0,0H1,1H0,1H1 (16 loads, FIFO); read 0H0 -> setA ----
    STG_HALF(0, 0);
    STG_HALF(0, 1);
    STG_HALF(1, 0);
    STG_HALF(1, 1);
    asm volatile("s_waitcnt vmcnt(12)" ::: "memory");   // drain 0H0
    BAR;
    READ_SET(avA, bvA, smem, 0);

    // ---- steady loop: u = 0..29 (phases 2u, 2u+1) ----
    for (int u = 0; u < NT - 2; ++u) {
        signed char* bufc = smem + (u & 1) * 65536;
        signed char* bufn = smem + ((u + 1) & 1) * 65536;
        // phase 2u: MFMA half 2u (setA), read half 2u+1 -> setB, stage (u+2).H0
        asm volatile("s_waitcnt vmcnt(8)" ::: "memory");   // drain half 2u+1
        BAR;
        STG_HALF(u + 2, 0);
        READ_SET(avB, bvB, bufc, 1);
        MFMA_SET(avA, bvA);
        LGKM0;
        // phase 2u+1: MFMA half 2u+1 (setB), read half 2u+2 -> setA, stage (u+2).H1
        asm volatile("s_waitcnt vmcnt(8)" ::: "memory");   // drain half 2u+2
        BAR;
        STG_HALF(u + 2, 1);
        READ_SET(avA, bvA, bufn, 0);
        MFMA_SET(avB, bvB);
        LGKM0;
    }

    // ---- u = 30 (phases 60, 61): no more staging ----
    {
        signed char* bufc = smem;            // buf[0]
        signed char* bufn = smem + 65536;    // buf[1]
        asm volatile("s_waitcnt vmcnt(8)" ::: "memory");   // drain half 61
        BAR;
        READ_SET(avB, bvB, bufc, 1);
        MFMA_SET(avA, bvA);
        LGKM0;
        asm volatile("s_waitcnt vmcnt(4)" ::: "memory");   // drain half 62
        BAR;
        READ_SET(avA, bvA, bufn, 0);
        MFMA_SET(avB, bvB);
        LGKM0;
    }
    // ---- u = 31 (phases 62, 63) ----
    {
        signed char* bufc = smem + 65536;    // buf[1]
        asm volatile("s_waitcnt vmcnt(0)" ::: "memory");   // drain half 63
        BAR;
        READ_SET(avB, bvB, bufc, 1);
        MFMA_SET(avA, bvA);
        LGKM0;
        MFMA_SET(avB, bvB);                  // final half, no reads
    }

    // ---- epilogue: dequant + bias, fp32 store ----
    // 16x16 C/D map: col = lane&15, row = (lane>>4)*4 + reg
    const int orow0 = bm + wr * 128;
    const int ocol0 = bn + wc * 64;
    float wsv[4], bvv[4];
#pragma unroll
    for (int g = 0; g < 4; ++g) {
        const int col = ocol0 + g * 16 + frow;
        wsv[g] = wsc[col];
        bvv[g] = bias[col];
    }
#pragma unroll
    for (int f = 0; f < 8; ++f) {
#pragma unroll
        for (int jr = 0; jr < 4; ++jr) {
            const int row = orow0 + f * 16 + fsl * 4 + jr;
            const float s = sx[row];
#pragma unroll
            for (int g = 0; g < 4; ++g) {
                const int col = ocol0 + g * 16 + frow;
                C[(size_t)row * Ndim + col] = (float)acc[f][g][jr] * s * wsv[g] + bvv[g];
            }
        }
    }
#undef STG_HALF
#undef READ_SET
#undef MFMA_SET
#undef BAR
#undef LGKM0
}

extern "C" void kernel_launch(void* const* d_in, const int* in_sizes, int n_in,
                              void* d_out, int out_size, void* d_ws, size_t ws_size,
                              hipStream_t stream) {
    (void)in_sizes; (void)n_in; (void)out_size; (void)ws_size;
    const int*   x_q  = (const int*)d_in[0];
    const float* sx   = (const float*)d_in[1];
    const int*   w_q  = (const int*)d_in[2];
    const float* wsc  = (const float*)d_in[3];
    const float* bias = (const float*)d_in[4];
    float* out = (float*)d_out;

    signed char* x8 = (signed char*)d_ws;
    signed char* w8 = x8 + (size_t)MtotC * Kdim;

    const size_t nx = (size_t)MtotC * Kdim;   // 32 Mi
    const size_t nw = (size_t)Ndim * Kdim;    // 16 Mi

    pack_i32_to_i8<<<3072, 256, 0, stream>>>(x_q, w_q, x8, w8, nx / 4, nw / 4);

    static bool attr_set = false;
    if (!attr_set) {
        hipFuncSetAttribute((const void*)i8gemm_kernel,
                            hipFuncAttributeMaxDynamicSharedMemorySize, 131072);
        attr_set = true;
    }

    const int nwg = (MtotC / BM) * (Ndim / BN);  // 512
    i8gemm_kernel<<<nwg, 512, 131072, stream>>>(x8, w8, sx, wsc, bias, out);
}